// Round 5
// baseline (98.394 us; speedup 1.0000x reference)
//
#include <hip/hip_runtime.h>

#define IMG_H 224
#define IMG_W 224
#define NPIX (IMG_H * IMG_W)        // 50176
#define NG 1024

#define TILE_W 32
#define TILE_H 16
#define TXN (IMG_W / TILE_W)        // 7
#define TYN (IMG_H / TILE_H)        // 14
#define NTILE (TXN * TYN)           // 98
#define NSLICE 8
#define CAP NG                      // worst-case per-tile entries (safe)

#define K_EXP  -0.72134752044448170368f   // -0.5 * log2(e)
#define ELIM   -21.640425613334451f       // 30 * K_EXP  (min(dist,30))
#define W15     3.0590232050182579e-07f   // exp(-15) = 2^ELIM

// ws layout:
//   [0, 392)    int counts[98]
//   [512, 524)  float S[3]
//   [4096, ...) per-tile slabs: 2*float4 per entry, CAP entries, 32 KiB/tile
#define WS_CNT_OFF   0
#define WS_S_OFF     512
#define WS_SLAB_OFF  4096
#define SLAB_F4      ((size_t)CAP * 2)                 // float4s per tile slab
#define WS_NEED      (WS_SLAB_OFF + (size_t)NTILE * CAP * 32)   // ~3.2 MiB

// ---------- pass 1: params + background sum + branch-free tile binning ----------
__global__ __launch_bounds__(64) void prep_bin_kernel(
    const float* __restrict__ alpha,
    const float* __restrict__ color,
    const float* __restrict__ offset,
    const float* __restrict__ scale,
    const float* __restrict__ rotation,
    const float* __restrict__ basep,
    const float* __restrict__ iw,
    int* __restrict__ counts,
    float* __restrict__ S,
    float4* __restrict__ slabs)
{
    const int g = blockIdx.x * 64 + (int)threadIdx.x;   // grid = 16 x 64 = 1024
    float cx = fminf(fmaxf(basep[2*g]   + offset[2*g],   0.f), 224.f);
    float cy = fminf(fmaxf(basep[2*g+1] + offset[2*g+1], 0.f), 224.f);
    float cr_ = cosf(rotation[g]);
    float sr_ = sinf(rotation[g]);
    float s1q = scale[2*g]   * scale[2*g];
    float s2q = scale[2*g+1] * scale[2*g+1];
    float c00 = cr_*cr_*s1q + sr_*sr_*s2q + 1e-4f;
    float c01 = cr_*sr_*(s1q - s2q);
    float c11 = sr_*sr_*s1q + cr_*cr_*s2q + 1e-4f;
    // ellipse {dist<=30} axis-aligned extents: |dx|<=sqrt(30*cov00), |dy|<=sqrt(30*cov11)
    float rx = sqrtf(30.f * c00);
    float ry = sqrtf(30.f * c11);
    float rdet = 1.0f / (c00*c11 - c01*c01);
    float A =  K_EXP * c11 * rdet;
    float B = -2.0f * K_EXP * c01 * rdet;
    float C =  K_EXP * c00 * rdet;
    float a = alpha[g] * iw[g];
    float qr = a * color[3*g];
    float qg = a * color[3*g+1];
    float qb = a * color[3*g+2];

    // background sum: wave reduce, 3 atomics per wave
    float vr = qr, vg = qg, vb = qb;
    #pragma unroll
    for (int o = 32; o >= 1; o >>= 1) {
        vr += __shfl_down(vr, o);
        vg += __shfl_down(vg, o);
        vb += __shfl_down(vb, o);
    }
    if ((int)threadIdx.x == 0) {
        atomicAdd(&S[0], vr); atomicAdd(&S[1], vg); atomicAdd(&S[2], vb);
    }

    // tile bbox (intersecting tiles)
    const int tx0 = max(0,       (int)floorf((cx - rx) * (1.0f/TILE_W)));
    const int tx1 = min(TXN - 1, (int)floorf((cx + rx) * (1.0f/TILE_W)));
    const int ty0 = max(0,       (int)floorf((cy - ry) * (1.0f/TILE_H)));
    const int ty1 = min(TYN - 1, (int)floorf((cy + ry) * (1.0f/TILE_H)));

    const float4 e0 = make_float4(cx, cy, A, B);
    const float4 e1 = make_float4(C, qr, qg, qb);
    for (int ty = ty0; ty <= ty1; ++ty) {
        for (int tx = tx0; tx <= tx1; ++tx) {
            const int t = ty * TXN + tx;
            const int idx = atomicAdd(&counts[t], 1);
            float4* dst = slabs + (size_t)t * SLAB_F4 + (size_t)idx * 2;
            dst[0] = e0;
            dst[1] = e1;
        }
    }
}

// ---------- pass 2: raster; contiguous branch-free entry loop, 2 px/thread ----------
__global__ __launch_bounds__(256) void raster_kernel(
    const int* __restrict__ counts,
    const float* __restrict__ S,
    const float4* __restrict__ slabs,
    float* __restrict__ out)
{
    const int bx = blockIdx.x, by = blockIdx.y, z = blockIdx.z;
    const int t = by * TXN + bx;
    const int n = counts[t];
    const int lo = (n * z) >> 3;
    const int hi = (n * (z + 1)) >> 3;

    const int tid = (int)threadIdx.x;
    const int lx = (tid & 15) << 1;        // 0,2,...,30
    const int ly = tid >> 4;               // 0..15
    const int ipx = bx * TILE_W + lx;
    const int ipy = by * TILE_H + ly;
    const float px = (float)ipx;
    const float py = (float)ipy;

    float r0, g0, b0, r1, g1, b1;
    if (z == 0) {                          // slice 0 carries the exact background
        float s0 = S[0], s1 = S[1], s2 = S[2];
        r0 = W15 * s0; g0 = W15 * s1; b0 = W15 * s2;
        r1 = r0; g1 = g0; b1 = b0;
    } else {
        r0 = g0 = b0 = r1 = g1 = b1 = 0.f;
    }

    const float4* __restrict__ sl = slabs + (size_t)t * SLAB_F4;
    for (int i = lo; i < hi; ++i) {
        const float4 qa = sl[2*i];         // uniform index -> scalar loads
        const float4 qb = sl[2*i + 1];
        const float cx = qa.x, cy = qa.y, A = qa.z, Bc = qa.w;
        const float Cc = qb.x, cr = qb.y, cg = qb.z, cb = qb.w;
        float dy  = py - cy;
        float tt  = Bc * dy;
        float w2  = Cc * (dy * dy);
        float dx0 = px - cx;
        float u0  = fmaf(A, dx0, tt);
        float e0  = fmaf(dx0, u0, w2);
        float u1  = u0 + A;
        float e1  = fmaf(dx0 + 1.0f, u1, w2);
        e0 = fmaxf(e0, ELIM);
        e1 = fmaxf(e1, ELIM);
        float w0 = __builtin_amdgcn_exp2f(e0) - W15;   // exact background cancel
        float w1 = __builtin_amdgcn_exp2f(e1) - W15;
        r0 = fmaf(w0, cr, r0);  r1 = fmaf(w1, cr, r1);
        g0 = fmaf(w0, cg, g0);  g1 = fmaf(w1, cg, g1);
        b0 = fmaf(w0, cb, b0);  b1 = fmaf(w1, cb, b1);
    }

    const int p0 = ipy * IMG_W + ipx;
    atomicAdd(&out[p0],            r0);  atomicAdd(&out[p0 + 1],            r1);
    atomicAdd(&out[NPIX + p0],     g0);  atomicAdd(&out[NPIX + p0 + 1],     g1);
    atomicAdd(&out[2*NPIX + p0],   b0);  atomicAdd(&out[2*NPIX + p0 + 1],   b1);
}

// ---------- fallback (ws too small): round-2 dense LDS version ----------
#define SPLIT 8
#define GPS (NG / SPLIT)
struct __align__(16) GParam { float cx, cy, A, B, C, cr, cg, cb; };

__global__ __launch_bounds__(256) void raster_lds_kernel(
    const float* __restrict__ alpha,
    const float* __restrict__ color,
    const float* __restrict__ offset,
    const float* __restrict__ scale,
    const float* __restrict__ rotation,
    const float* __restrict__ basep,
    const float* __restrict__ iw,
    float* __restrict__ out)
{
    __shared__ GParam gp[GPS];
    const int tid = (int)threadIdx.x;
    if (tid < GPS) {
        const int g = blockIdx.y * GPS + tid;
        float cx = fminf(fmaxf(basep[2*g]   + offset[2*g],   0.f), 224.f);
        float cy = fminf(fmaxf(basep[2*g+1] + offset[2*g+1], 0.f), 224.f);
        float cr_ = cosf(rotation[g]);
        float sr_ = sinf(rotation[g]);
        float s1q = scale[2*g]   * scale[2*g];
        float s2q = scale[2*g+1] * scale[2*g+1];
        float c00 = cr_*cr_*s1q + sr_*sr_*s2q + 1e-4f;
        float c01 = cr_*sr_*(s1q - s2q);
        float c11 = sr_*sr_*s1q + cr_*cr_*s2q + 1e-4f;
        float rdet = 1.0f / (c00*c11 - c01*c01);
        GParam q;
        q.cx = cx; q.cy = cy;
        q.A =  K_EXP * c11 * rdet;
        q.B = -2.0f * K_EXP * c01 * rdet;
        q.C =  K_EXP * c00 * rdet;
        float a = alpha[g] * iw[g];
        q.cr = a * color[3*g];
        q.cg = a * color[3*g+1];
        q.cb = a * color[3*g+2];
        gp[tid] = q;
    }
    __syncthreads();

    const int p = blockIdx.x * 256 + tid;
    const float px = (float)(p % IMG_W);
    const float py = (float)(p / IMG_W);
    float r = 0.f, g = 0.f, b = 0.f;
    #pragma unroll 4
    for (int i = 0; i < GPS; ++i) {
        GParam q = gp[i];
        float dx = px - q.cx;
        float dy = py - q.cy;
        float e = fmaf(dx, fmaf(q.A, dx, q.B * dy), q.C * (dy * dy));
        e = fmaxf(e, ELIM);
        float w = __builtin_amdgcn_exp2f(e);
        r = fmaf(w, q.cr, r);
        g = fmaf(w, q.cg, g);
        b = fmaf(w, q.cb, b);
    }
    atomicAdd(&out[p],          r);
    atomicAdd(&out[NPIX + p],   g);
    atomicAdd(&out[2*NPIX + p], b);
}

extern "C" void kernel_launch(void* const* d_in, const int* in_sizes, int n_in,
                              void* d_out, int out_size, void* d_ws, size_t ws_size,
                              hipStream_t stream)
{
    const float* alpha    = (const float*)d_in[0];
    const float* color    = (const float*)d_in[1];
    const float* offset   = (const float*)d_in[2];
    const float* scale    = (const float*)d_in[3];
    const float* rotation = (const float*)d_in[4];
    const float* basep    = (const float*)d_in[5];
    const float* iw       = (const float*)d_in[6];
    float* out = (float*)d_out;

    hipMemsetAsync(out, 0, (size_t)out_size * sizeof(float), stream);

    if (ws_size >= WS_NEED) {
        int*    counts = (int*)((char*)d_ws + WS_CNT_OFF);
        float*  S      = (float*)((char*)d_ws + WS_S_OFF);
        float4* slabs  = (float4*)((char*)d_ws + WS_SLAB_OFF);

        hipMemsetAsync(d_ws, 0, 1024, stream);   // zero counts + S
        prep_bin_kernel<<<NG / 64, 64, 0, stream>>>(
            alpha, color, offset, scale, rotation, basep, iw, counts, S, slabs);
        raster_kernel<<<dim3(TXN, TYN, NSLICE), 256, 0, stream>>>(
            counts, S, slabs, out);
    } else {
        dim3 grid(NPIX / 256, SPLIT);
        raster_lds_kernel<<<grid, 256, 0, stream>>>(
            alpha, color, offset, scale, rotation, basep, iw, out);
    }
}

// Round 6
// 72.510 us; speedup vs baseline: 1.3570x; 1.3570x over previous
//
#include <hip/hip_runtime.h>

#define IMG_H 224
#define IMG_W 224
#define NPIX (IMG_H * IMG_W)        // 50176
#define NG 1024
#define TILE 16
#define TXN (IMG_W / TILE)          // 14
#define TYN (IMG_H / TILE)          // 14  -> 196 blocks
#define GPT (NG / 256)              // 4 gaussians per thread in prep phase

#define K_EXP  -0.72134752044448170368f   // -0.5 * log2(e)
#define ELIM   -21.640425613334451f       // 30 * K_EXP  (min(dist,30))
#define W15     3.0590232050182579e-07f   // exp(-15) = 2^ELIM

// Single fused kernel: per-block param compute + tile cull (LDS compaction) + raster.
// Exactness: out-of-AABB => dist >= 30 => clamped weight == exp(-15) == W15 exactly,
// so unlisted gaussians contribute W15 * (a*color), covered by the background term
// W15 * S; listed gaussians accumulate (w - W15) to cancel their background share.
__global__ __launch_bounds__(256) void fused_raster_kernel(
    const float* __restrict__ alpha,
    const float* __restrict__ color,
    const float* __restrict__ offset,
    const float* __restrict__ scale,
    const float* __restrict__ rotation,
    const float* __restrict__ basep,
    const float* __restrict__ iw,
    float* __restrict__ out)
{
    __shared__ float4 list[NG * 2];   // 32 KiB: 2 x float4 per accepted gaussian
    __shared__ float  sred[4][3];
    __shared__ int    cnt;

    const int tid = (int)threadIdx.x;
    if (tid == 0) cnt = 0;
    __syncthreads();

    const int bx0 = blockIdx.x * TILE;
    const int by0 = blockIdx.y * TILE;
    const float txmin = (float)bx0, txmax = (float)(bx0 + TILE - 1);
    const float tymin = (float)by0, tymax = (float)(by0 + TILE - 1);

    const float2* __restrict__ off2   = (const float2*)offset;
    const float2* __restrict__ scale2 = (const float2*)scale;
    const float2* __restrict__ base2  = (const float2*)basep;

    float sr = 0.f, sg = 0.f, sb = 0.f;

    #pragma unroll
    for (int k = 0; k < GPT; ++k) {
        const int g = tid + k * 256;                 // coalesced across threads
        const float2 of = off2[g];
        const float2 bp = base2[g];
        const float2 sc = scale2[g];
        const float rot = rotation[g];
        const float a   = alpha[g] * iw[g];

        float cx = fminf(fmaxf(bp.x + of.x, 0.f), 224.f);
        float cy = fminf(fmaxf(bp.y + of.y, 0.f), 224.f);
        float cr_ = cosf(rot);
        float sr_ = sinf(rot);
        float s1q = sc.x * sc.x;
        float s2q = sc.y * sc.y;
        float c00 = cr_*cr_*s1q + sr_*sr_*s2q + 1e-4f;
        float c01 = cr_*sr_*(s1q - s2q);
        float c11 = sr_*sr_*s1q + cr_*cr_*s2q + 1e-4f;
        // exact axis-aligned extents of the {dist <= 30} ellipse
        float rx = sqrtf(30.f * c00);
        float ry = sqrtf(30.f * c11);
        float rdet = 1.0f / (c00*c11 - c01*c01);
        float A =  K_EXP * c11 * rdet;
        float B = -2.0f * K_EXP * c01 * rdet;
        float C =  K_EXP * c00 * rdet;
        float qr = a * color[3*g];
        float qg = a * color[3*g+1];
        float qb = a * color[3*g+2];

        sr += qr; sg += qg; sb += qb;

        bool hit = (cx - rx <= txmax) & (cx + rx >= txmin) &
                   (cy - ry <= tymax) & (cy + ry >= tymin);
        if (hit) {
            int idx = atomicAdd(&cnt, 1);            // LDS atomic
            list[2*idx]     = make_float4(cx, cy, A, B);
            list[2*idx + 1] = make_float4(C, qr, qg, qb);
        }
    }

    // block reduction of background color sum (deterministic order)
    #pragma unroll
    for (int o = 32; o >= 1; o >>= 1) {
        sr += __shfl_down(sr, o);
        sg += __shfl_down(sg, o);
        sb += __shfl_down(sb, o);
    }
    const int wid = tid >> 6;
    if ((tid & 63) == 0) { sred[wid][0] = sr; sred[wid][1] = sg; sred[wid][2] = sb; }
    __syncthreads();

    const float S0 = sred[0][0] + sred[1][0] + sred[2][0] + sred[3][0];
    const float S1 = sred[0][1] + sred[1][1] + sred[2][1] + sred[3][1];
    const float S2 = sred[0][2] + sred[1][2] + sred[2][2] + sred[3][2];
    const int n = cnt;

    const int lx = tid & 15;
    const int ly = tid >> 4;
    const float px = (float)(bx0 + lx);
    const float py = (float)(by0 + ly);

    float r = W15 * S0;
    float g = W15 * S1;
    float b = W15 * S2;

    #pragma unroll 4
    for (int i = 0; i < n; ++i) {
        const float4 qa = list[2*i];        // wave-uniform -> LDS broadcast
        const float4 qc = list[2*i + 1];
        float dx = px - qa.x;
        float dy = py - qa.y;
        float e  = fmaf(dx, fmaf(qa.z, dx, qa.w * dy), qc.x * (dy * dy));
        e = fmaxf(e, ELIM);
        float w = __builtin_amdgcn_exp2f(e) - W15;   // cancels background exactly
        r = fmaf(w, qc.y, r);
        g = fmaf(w, qc.z, g);
        b = fmaf(w, qc.w, b);
    }

    const int p = (by0 + ly) * IMG_W + bx0 + lx;
    out[p]            = r;
    out[NPIX + p]     = g;
    out[2*NPIX + p]   = b;
}

extern "C" void kernel_launch(void* const* d_in, const int* in_sizes, int n_in,
                              void* d_out, int out_size, void* d_ws, size_t ws_size,
                              hipStream_t stream)
{
    const float* alpha    = (const float*)d_in[0];
    const float* color    = (const float*)d_in[1];
    const float* offset   = (const float*)d_in[2];
    const float* scale    = (const float*)d_in[3];
    const float* rotation = (const float*)d_in[4];
    const float* basep    = (const float*)d_in[5];
    const float* iw       = (const float*)d_in[6];
    float* out = (float*)d_out;

    fused_raster_kernel<<<dim3(TXN, TYN), 256, 0, stream>>>(
        alpha, color, offset, scale, rotation, basep, iw, out);
}